// Round 9
// baseline (186.028 us; speedup 1.0000x reference)
//
#include <hip/hip_runtime.h>

// out[b,a,x,y] = C0 * (s x Fn)[a], Fn = periodic 4-neighbor sum of s.
// L[s][r][a] = -eps_{sra}; 6 nonzero coefficients loaded from Lp, -C0 folded in.
// Epilogue uses the EXPLICIT per-a pairing verified rounds 1-2/6/7/8 (absmax=0):
//   o[0] = cA0*(sc1*Fn2) + cB0*(sc2*Fn1)
//   o[1] = cA1*(sc0*Fn2) + cB1*(sc2*Fn0)
//   o[2] = cA2*(sc0*Fn1) + cB2*(sc1*Fn0)
// (cyclic (a+1)%3 form silently sign-flips the a=1 plane - do not "simplify".)
//
// Round 9: persistent pipelined blocks - never drain the read queue.
// All 7 prior mechanisms null; remaining theory: every prior kernel alternated
// {issue loads -> vmcnt(0) drain -> compute -> store -> block end}, so the
// memory pipe runs at ~55% duty cycle = the observed 3.3/6.3 TB/s.
// Here each block walks 16 granules (2 rows each) of a 32-row strip through an
// 8-row LDS ring: granule g+2's async global_load_lds are ALWAYS in flight
// while granule g computes/stores. Counted s_waitcnt vmcnt(3) + raw s_barrier
// (T3/T4 pattern) - vmcnt(0) only on the last granule.
// Ring safety: compute g reads rows 2g-1..2g+2 (slots &7), in-flight writes
// rows 2g+5..2g+6 even with one-barrier skew -> span 7 < 8, disjoint.

constexpr int B = 32, X = 512, Y = 512;
constexpr int XY = X * Y;
constexpr int STRIP = 32;          // output rows per block
constexpr int NG = STRIP / 2;      // 16 compute granules (2 rows each)
constexpr int RING = 8;            // LDS ring rows (48 KB total)

typedef float f32x4 __attribute__((ext_vector_type(4)));

__device__ __forceinline__ void nt_store4(float* p, float a, float b, float c, float d)
{
    f32x4 v = { a, b, c, d };
    __builtin_nontemporal_store(v, (f32x4*)p);
}

__global__ __launch_bounds__(256)
void psi0_kernel(const float* __restrict__ s,
                 const float* __restrict__ C0p,
                 const float* __restrict__ Lp,
                 float* __restrict__ out)
{
    __shared__ __align__(16) float lds[RING][3][Y];   // 8*3*512*4 = 49152 B

    const int tid  = threadIdx.x;
    const int lane = tid & 63;
    const int wv   = tid >> 6;                        // 4 waves

    const int bid = blockIdx.x;
    const int b   = bid >> 4;                         // 16 strips per batch
    const int xs  = (bid & 15) * STRIP;               // strip start (abs row)

    const size_t base = (size_t)b * 3 * XY;

    // Stage granule h: rows (xs+2h-1, xs+2h) x 3 comps x 2 half-rows.
    // 12 block-wide 1KB direct-to-LDS loads; wave wv issues idx 3wv..3wv+2.
    // LDS dest is wave-uniform base (HW adds lane*16); source is per-lane.
    auto stage = [&](int h) {
        #pragma unroll
        for (int k = 0; k < 3; ++k) {
            const int idx = wv * 3 + k;               // 0..11
            const int j   = idx & 1;                  // half-row
            const int rc  = idx >> 1;                 // 0..5
            const int cc  = rc % 3;                   // component
            const int rr  = rc / 3;                   // 0 or 1
            const int axs  = xs + 2 * h - 1 + rr;     // unwrapped abs row
            const int xg   = axs & (X - 1);           // wrapped global row
            const int slot = axs & (RING - 1);        // ring slot
            const float* gp = s + base + (size_t)cc * XY + (size_t)xg * Y
                              + j * 256 + lane * 4;
            __builtin_amdgcn_global_load_lds(
                (const __attribute__((address_space(1))) void*)gp,
                (__attribute__((address_space(3))) void*)(&lds[slot][cc][j * 256]),
                16, 0, 0);
        }
    };

    const float C0  = C0p[0];
    const float cA0 = -C0 * Lp[15];  // a=0: (s=1,r=2)
    const float cB0 = -C0 * Lp[21];  // a=0: (s=2,r=1)
    const float cA1 = -C0 * Lp[7];   // a=1: (s=0,r=2)
    const float cB1 = -C0 * Lp[19];  // a=1: (s=2,r=0)
    const float cA2 = -C0 * Lp[5];   // a=2: (s=0,r=1)
    const float cB2 = -C0 * Lp[11];  // a=2: (s=1,r=0)

    // prologue: granules 0 and 1 in flight (6 loads/wave)
    stage(0);
    stage(1);

    #pragma unroll 1
    for (int g = 0; g < NG; ++g) {
        // keep the pipe full: issue g+2 BEFORE waiting; wait only until the
        // newest granule's 3 loads may remain (g+1 and older complete).
        if (g + 2 <= NG) {                            // stage granules h=0..NG
            stage(g + 2);
            asm volatile("s_waitcnt vmcnt(3)" ::: "memory");
        } else {
            asm volatile("s_waitcnt vmcnt(0)" ::: "memory");
        }
        __builtin_amdgcn_sched_barrier(0);
        __builtin_amdgcn_s_barrier();   // raw barrier: no compiler vmcnt(0) drain

        // compute granule g: rows 2g (waves 0,1) and 2g+1 (waves 2,3)
        const int r0 = (g << 1) + (tid >> 7);
        const int ax = xs + r0;                       // <= 511, no wrap
        const int y0 = (tid & 127) << 2;
        const int ym = (y0 - 1) & (Y - 1);
        const int yp = (y0 + 4) & (Y - 1);
        const int sC = ax & (RING - 1);
        const int sU = (ax - 1) & (RING - 1);
        const int sD = (ax + 1) & (RING - 1);

        float sc[3][4], Fn[3][4];
        #pragma unroll
        for (int c = 0; c < 3; ++c) {
            const float* lc = &lds[sC][c][0];
            const f32x4 cc = *(const f32x4*)(lc + y0);
            const f32x4 uu = *(const f32x4*)(&lds[sU][c][y0]);
            const f32x4 dd = *(const f32x4*)(&lds[sD][c][y0]);
            const float lf = lc[ym];
            const float rt = lc[yp];

            sc[c][0] = cc.x; sc[c][1] = cc.y; sc[c][2] = cc.z; sc[c][3] = cc.w;
            Fn[c][0] = uu.x + dd.x + lf   + cc.y;
            Fn[c][1] = uu.y + dd.y + cc.x + cc.z;
            Fn[c][2] = uu.z + dd.z + cc.y + cc.w;
            Fn[c][3] = uu.w + dd.w + cc.z + rt;
        }

        float o0[4], o1[4], o2[4];
        #pragma unroll
        for (int e = 0; e < 4; ++e) {
            o0[e] = cA0 * (sc[1][e] * Fn[2][e]) + cB0 * (sc[2][e] * Fn[1][e]);
            o1[e] = cA1 * (sc[0][e] * Fn[2][e]) + cB1 * (sc[2][e] * Fn[0][e]);
            o2[e] = cA2 * (sc[0][e] * Fn[1][e]) + cB2 * (sc[1][e] * Fn[0][e]);
        }

        const size_t ro_off = (size_t)ax * Y + y0;
        nt_store4(out + base + 0 * (size_t)XY + ro_off, o0[0], o0[1], o0[2], o0[3]);
        nt_store4(out + base + 1 * (size_t)XY + ro_off, o1[0], o1[1], o1[2], o1[3]);
        nt_store4(out + base + 2 * (size_t)XY + ro_off, o2[0], o2[1], o2[2], o2[3]);
    }
}

extern "C" void kernel_launch(void* const* d_in, const int* in_sizes, int n_in,
                              void* d_out, int out_size, void* d_ws, size_t ws_size,
                              hipStream_t stream)
{
    const float* s   = (const float*)d_in[0];
    // d_in[1] = t (unused: coeff is t-independent with a single cc entry)
    const float* C0p = (const float*)d_in[2];
    const float* Lp  = (const float*)d_in[3];
    float* out = (float*)d_out;

    const int blocks = B * (X / STRIP);   // 512 blocks x 256 threads; 2/CU resident
    psi0_kernel<<<blocks, 256, 0, stream>>>(s, C0p, Lp, out);
}